// Round 21
// baseline (300.634 us; speedup 1.0000x reference)
//
#include <hip/hip_runtime.h>
#include <math.h>

#define BB     1024
#define CC     256
#define HWN    361
#define SEH    64
#define P3C    768
#define SLICE  (CC * HWN)      // 92416 floats per batch row
#define NW     16

typedef _Float16 f16x2 __attribute__((ext_vector_type(2)));

__device__ __forceinline__ unsigned pack2(float a, float b) {
    f16x2 h; h[0] = (_Float16)a; h[1] = (_Float16)b;
    return __builtin_bit_cast(unsigned, h);
}

// R12 champion with the MLP rebuilt wave-parallel + coalesced:
// layer1: wave wv -> outputs 4wv..4wv+3, lanes read w1 rows coalesced
//         (256B wave-loads), butterfly reduce; no more 3KB-stride gathers.
// layer2: wave wv -> outputs 32wv..32wv+31, one coalesced w2-row load each.
// Pool and apply phases are R12 verbatim (pinned f16 payload, zero re-read).
__global__ __launch_bounds__(1024, 4) void k_se_fused(
        const float* __restrict__ x,
        const float* __restrict__ mask,
        const float* __restrict__ msum,
        const float* __restrict__ msqrt,
        const float* __restrict__ w1,
        const float* __restrict__ b1,
        const float* __restrict__ w2,
        const float* __restrict__ b2,
        float* __restrict__ out) {
    __shared__ float m_s[HWN];
    __shared__ float p_s[P3C];
    __shared__ float hid_s[SEH];
    __shared__ float g_s[CC];
    __shared__ float be_s[CC];

    const int tid  = threadIdx.x;
    const int lane = tid & 63;
    const int wv   = tid >> 6;          // 0..15
    const int b    = blockIdx.x;

    const float* xb = x + (size_t)b * SLICE;

    if (tid < HWN) m_s[tid] = mask[(size_t)b * HWN + tid];
    __syncthreads();

    const float inv_div = 1.0f / msum[b];
    const float bscale  = (msqrt[b] - 14.0f) * 0.1f;   // (sqrt(div)-B_AVG)/10

    const int  i5   = lane + 320;
    const int  a5   = (i5 < HWN) ? i5 : (HWN - 1);
    const bool tail = (lane < 41);

    unsigned pk[16][3];                 // packed f16 payload, static indices

    // ---- pool + pack (R12 verbatim) ----
    #pragma unroll
    for (int k = 0; k < 16; k += 2) {
        const int c0 = wv * 16 + k;
        const float* r0 = xb + c0 * HWN;
        const float* r1 = r0 + HWN;
        float v[6], w[6];
        #pragma unroll
        for (int ii = 0; ii < 5; ++ii) {
            v[ii] = r0[lane + ii * 64];
            w[ii] = r1[lane + ii * 64];
        }
        v[5] = r0[a5];
        w[5] = r1[a5];

        pk[k][0]     = pack2(v[0], v[1]);
        pk[k][1]     = pack2(v[2], v[3]);
        pk[k][2]     = pack2(v[4], v[5]);
        pk[k + 1][0] = pack2(w[0], w[1]);
        pk[k + 1][1] = pack2(w[2], w[3]);
        pk[k + 1][2] = pack2(w[4], w[5]);
        asm volatile("" : "+v"(pk[k][0]), "+v"(pk[k][1]), "+v"(pk[k][2]),
                          "+v"(pk[k+1][0]), "+v"(pk[k+1][1]), "+v"(pk[k+1][2]));

        float s0 = 0.0f, s1 = 0.0f, x0 = -INFINITY, x1 = -INFINITY;
        #pragma unroll
        for (int ii = 0; ii < 5; ++ii) {
            const float pen = (1.0f - m_s[lane + ii * 64]) * -5000.0f;
            s0 += v[ii];  x0 = fmaxf(x0, v[ii] + pen);
            s1 += w[ii];  x1 = fmaxf(x1, w[ii] + pen);
        }
        if (tail) {
            const float pen = (1.0f - m_s[i5]) * -5000.0f;
            s0 += v[5];   x0 = fmaxf(x0, v[5] + pen);
            s1 += w[5];   x1 = fmaxf(x1, w[5] + pen);
        }
        #pragma unroll
        for (int off = 32; off; off >>= 1) {
            s0 += __shfl_xor(s0, off);  x0 = fmaxf(x0, __shfl_xor(x0, off));
            s1 += __shfl_xor(s1, off);  x1 = fmaxf(x1, __shfl_xor(x1, off));
        }
        if (lane == 0) {
            const float mean0 = s0 * inv_div, mean1 = s1 * inv_div;
            p_s[c0]           = mean0;
            p_s[256 + c0]     = mean0 * bscale;
            p_s[512 + c0]     = x0;
            p_s[c0 + 1]       = mean1;
            p_s[256 + c0 + 1] = mean1 * bscale;
            p_s[512 + c0 + 1] = x1;
        }
    }
    __syncthreads();

    // ---- layer 1 (768 -> 64), coalesced: wave wv -> outputs 4wv..4wv+3 ----
    {
        float pv[12];
        #pragma unroll
        for (int ii = 0; ii < 12; ++ii) pv[ii] = p_s[lane + 64 * ii];

        float acc[4];
        #pragma unroll
        for (int r = 0; r < 4; ++r) {
            const float* w1r = w1 + (wv * 4 + r) * P3C;
            float a = 0.0f;
            #pragma unroll
            for (int ii = 0; ii < 12; ++ii)
                a = fmaf(pv[ii], w1r[lane + 64 * ii], a);   // coalesced
            acc[r] = a;
        }
        #pragma unroll
        for (int off = 32; off; off >>= 1) {
            #pragma unroll
            for (int r = 0; r < 4; ++r) acc[r] += __shfl_xor(acc[r], off);
        }
        if (lane == 0) {
            #pragma unroll
            for (int r = 0; r < 4; ++r) {
                const int s = wv * 4 + r;
                hid_s[s] = fmaxf(acc[r] + b1[s], 0.0f);
            }
        }
    }
    __syncthreads();

    // ---- layer 2 (64 -> 512), coalesced: wave wv -> outputs 32wv..32wv+31 --
    {
        const float h = hid_s[lane];
        #pragma unroll 4
        for (int r = 0; r < 32; ++r) {
            const int o = wv * 32 + r;
            float a = h * w2[(size_t)o * SEH + lane];       // coalesced
            #pragma unroll
            for (int off = 32; off; off >>= 1) a += __shfl_xor(a, off);
            if (lane == 0) {
                a += b2[o];
                if (o < 256) g_s[o]        = 1.0f / (1.0f + __expf(-a));
                else         be_s[o - 256] = a;
            }
        }
    }
    __syncthreads();

    // ---- apply from pinned registers (R12 verbatim); zero reads ----
    float* ob = out + (size_t)b * SLICE;
    #pragma unroll
    for (int k = 0; k < 16; ++k) {
        const int c  = wv * 16 + k;
        const float g  = g_s[c];
        const float be = be_s[c];
        float* orow = ob + c * HWN;
        const f16x2 h0 = __builtin_bit_cast(f16x2, pk[k][0]);
        const f16x2 h1 = __builtin_bit_cast(f16x2, pk[k][1]);
        const f16x2 h2 = __builtin_bit_cast(f16x2, pk[k][2]);
        orow[lane]       = fmaf(g, (float)h0[0], be) * m_s[lane];
        orow[lane + 64]  = fmaf(g, (float)h0[1], be) * m_s[lane + 64];
        orow[lane + 128] = fmaf(g, (float)h1[0], be) * m_s[lane + 128];
        orow[lane + 192] = fmaf(g, (float)h1[1], be) * m_s[lane + 192];
        orow[lane + 256] = fmaf(g, (float)h2[0], be) * m_s[lane + 256];
        if (tail)
            orow[i5]     = fmaf(g, (float)h2[1], be) * m_s[i5];
    }
}

extern "C" void kernel_launch(void* const* d_in, const int* in_sizes, int n_in,
                              void* d_out, int out_size, void* d_ws, size_t ws_size,
                              hipStream_t stream) {
    const float* x     = (const float*)d_in[0];
    const float* mask  = (const float*)d_in[1];
    const float* msum  = (const float*)d_in[2];
    const float* msqrt = (const float*)d_in[3];
    const float* w1    = (const float*)d_in[4];
    const float* b1    = (const float*)d_in[5];
    const float* w2    = (const float*)d_in[6];
    const float* b2    = (const float*)d_in[7];
    float* out = (float*)d_out;

    k_se_fused<<<BB, 1024, 0, stream>>>(x, mask, msum, msqrt, w1, b1, w2, b2, out);
}

// Round 22
// 217.902 us; speedup vs baseline: 1.3797x; 1.3797x over previous
//
#include <hip/hip_runtime.h>
#include <math.h>

#define BB     1024
#define CC     256
#define HWN    361
#define SEH    64
#define P3C    768
#define SLICE  (CC * HWN)      // 92416 floats per batch row
#define NW     16
#define W1P    65              // padded s-dim for w1t (65 mod 32 = 1)
#define W2P    513             // padded o-dim for w2t (513 mod 32 = 1)
#define WBUFN  32832           // 64*513 floats = 131.3 KB (>= 384*65)

typedef _Float16 f16x2 __attribute__((ext_vector_type(2)));

__device__ __forceinline__ unsigned pack2(float a, float b) {
    f16x2 h; h[0] = (_Float16)a; h[1] = (_Float16)b;
    return __builtin_bit_cast(unsigned, h);
}

// R12 champion with LDS-staged transposed MLP weights:
// w1t[j][s] (pad 65) staged in 2 chunks, w2t[ss][o] (pad 513) -- all global
// reads coalesced 256B wave-loads, all LDS reads/writes conflict-free.
// Per-thread dots retained (R21's shuffle-reduce MLP regressed).
// Pool and apply phases are R12 verbatim (pinned f16 payload, zero re-read).
__global__ __launch_bounds__(1024, 4) void k_se_fused(
        const float* __restrict__ x,
        const float* __restrict__ mask,
        const float* __restrict__ msum,
        const float* __restrict__ msqrt,
        const float* __restrict__ w1,
        const float* __restrict__ b1,
        const float* __restrict__ w2,
        const float* __restrict__ b2,
        float* __restrict__ out) {
    __shared__ float wbuf[WBUFN];       // 131.3 KB weight staging (union)
    __shared__ float m_s[HWN];
    __shared__ float p_s[P3C];
    __shared__ float part_s[NW * SEH];
    __shared__ float hid_s[SEH];
    __shared__ float g_s[CC];
    __shared__ float be_s[CC];

    const int tid  = threadIdx.x;
    const int lane = tid & 63;
    const int wv   = tid >> 6;          // 0..15
    const int b    = blockIdx.x;

    const float* xb = x + (size_t)b * SLICE;

    if (tid < HWN) m_s[tid] = mask[(size_t)b * HWN + tid];
    __syncthreads();

    const float inv_div = 1.0f / msum[b];
    const float bscale  = (msqrt[b] - 14.0f) * 0.1f;   // (sqrt(div)-B_AVG)/10

    const int  i5   = lane + 320;
    const int  a5   = (i5 < HWN) ? i5 : (HWN - 1);
    const bool tail = (lane < 41);

    unsigned pk[16][3];                 // packed f16 payload, static indices

    // ---- pool + pack (R12 verbatim) ----
    #pragma unroll
    for (int k = 0; k < 16; k += 2) {
        const int c0 = wv * 16 + k;
        const float* r0 = xb + c0 * HWN;
        const float* r1 = r0 + HWN;
        float v[6], w[6];
        #pragma unroll
        for (int ii = 0; ii < 5; ++ii) {
            v[ii] = r0[lane + ii * 64];
            w[ii] = r1[lane + ii * 64];
        }
        v[5] = r0[a5];
        w[5] = r1[a5];

        pk[k][0]     = pack2(v[0], v[1]);
        pk[k][1]     = pack2(v[2], v[3]);
        pk[k][2]     = pack2(v[4], v[5]);
        pk[k + 1][0] = pack2(w[0], w[1]);
        pk[k + 1][1] = pack2(w[2], w[3]);
        pk[k + 1][2] = pack2(w[4], w[5]);
        asm volatile("" : "+v"(pk[k][0]), "+v"(pk[k][1]), "+v"(pk[k][2]),
                          "+v"(pk[k+1][0]), "+v"(pk[k+1][1]), "+v"(pk[k+1][2]));

        float s0 = 0.0f, s1 = 0.0f, x0 = -INFINITY, x1 = -INFINITY;
        #pragma unroll
        for (int ii = 0; ii < 5; ++ii) {
            const float pen = (1.0f - m_s[lane + ii * 64]) * -5000.0f;
            s0 += v[ii];  x0 = fmaxf(x0, v[ii] + pen);
            s1 += w[ii];  x1 = fmaxf(x1, w[ii] + pen);
        }
        if (tail) {
            const float pen = (1.0f - m_s[i5]) * -5000.0f;
            s0 += v[5];   x0 = fmaxf(x0, v[5] + pen);
            s1 += w[5];   x1 = fmaxf(x1, w[5] + pen);
        }
        #pragma unroll
        for (int off = 32; off; off >>= 1) {
            s0 += __shfl_xor(s0, off);  x0 = fmaxf(x0, __shfl_xor(x0, off));
            s1 += __shfl_xor(s1, off);  x1 = fmaxf(x1, __shfl_xor(x1, off));
        }
        if (lane == 0) {
            const float mean0 = s0 * inv_div, mean1 = s1 * inv_div;
            p_s[c0]           = mean0;
            p_s[256 + c0]     = mean0 * bscale;
            p_s[512 + c0]     = x0;
            p_s[c0 + 1]       = mean1;
            p_s[256 + c0 + 1] = mean1 * bscale;
            p_s[512 + c0 + 1] = x1;
        }
    }
    __syncthreads();

    // ---- layer 1 (768 -> 64): LDS-staged transposed weights, 2 chunks ----
    float acc1;
    {   // stage w1t chunk 0: j in [0,384): wave wv -> s rows 4wv..4wv+3
        #pragma unroll
        for (int r = 0; r < 4; ++r) {
            const int s = wv * 4 + r;
            #pragma unroll
            for (int ii = 0; ii < 6; ++ii) {
                const int j = lane + 64 * ii;
                wbuf[j * W1P + s] = w1[s * P3C + j];        // coalesced read
            }
        }
    }
    __syncthreads();
    {
        const int q = tid >> 6, s = tid & 63;
        acc1 = 0.0f;
        #pragma unroll
        for (int jj = 0; jj < 24; ++jj) {
            const int j = q * 24 + jj;
            acc1 = fmaf(p_s[j], wbuf[j * W1P + s], acc1);   // bcast + cf read
        }
    }
    __syncthreads();
    {   // stage w1t chunk 1: j in [384,768)
        #pragma unroll
        for (int r = 0; r < 4; ++r) {
            const int s = wv * 4 + r;
            #pragma unroll
            for (int ii = 0; ii < 6; ++ii) {
                const int j = lane + 64 * ii;
                wbuf[j * W1P + s] = w1[s * P3C + 384 + j];
            }
        }
    }
    __syncthreads();
    {
        const int q = tid >> 6, s = tid & 63;
        #pragma unroll
        for (int jj = 0; jj < 24; ++jj) {
            const int j = q * 24 + jj;
            acc1 = fmaf(p_s[384 + j], wbuf[j * W1P + s], acc1);
        }
        part_s[q * SEH + s] = acc1;
    }
    __syncthreads();

    // ---- hid reduce (tid<64) + stage w2t[ss][o] (all waves) ----
    if (tid < SEH) {
        float h = b1[tid];
        #pragma unroll
        for (int q = 0; q < NW; ++q) h += part_s[q * SEH + tid];
        hid_s[tid] = fmaxf(h, 0.0f);
    }
    {   // wave wv -> o rows 32wv..32wv+31; lane = ss
        #pragma unroll
        for (int r = 0; r < 32; ++r) {
            const int o = wv * 32 + r;
            wbuf[lane * W2P + o] = w2[o * SEH + lane];      // coalesced read
        }
    }
    __syncthreads();

    // ---- layer 2 (64 -> 512): per-thread dot from LDS, conflict-free ----
    if (tid < 512) {
        float a = b2[tid];
        #pragma unroll
        for (int ss = 0; ss < SEH; ++ss)
            a = fmaf(hid_s[ss], wbuf[ss * W2P + tid], a);
        if (tid < 256) g_s[tid]        = 1.0f / (1.0f + __expf(-a));
        else           be_s[tid - 256] = a;
    }
    __syncthreads();

    // ---- apply from pinned registers (R12 verbatim); zero reads ----
    float* ob = out + (size_t)b * SLICE;
    #pragma unroll
    for (int k = 0; k < 16; ++k) {
        const int c  = wv * 16 + k;
        const float g  = g_s[c];
        const float be = be_s[c];
        float* orow = ob + c * HWN;
        const f16x2 h0 = __builtin_bit_cast(f16x2, pk[k][0]);
        const f16x2 h1 = __builtin_bit_cast(f16x2, pk[k][1]);
        const f16x2 h2 = __builtin_bit_cast(f16x2, pk[k][2]);
        orow[lane]       = fmaf(g, (float)h0[0], be) * m_s[lane];
        orow[lane + 64]  = fmaf(g, (float)h0[1], be) * m_s[lane + 64];
        orow[lane + 128] = fmaf(g, (float)h1[0], be) * m_s[lane + 128];
        orow[lane + 192] = fmaf(g, (float)h1[1], be) * m_s[lane + 192];
        orow[lane + 256] = fmaf(g, (float)h2[0], be) * m_s[lane + 256];
        if (tail)
            orow[i5]     = fmaf(g, (float)h2[1], be) * m_s[i5];
    }
}

extern "C" void kernel_launch(void* const* d_in, const int* in_sizes, int n_in,
                              void* d_out, int out_size, void* d_ws, size_t ws_size,
                              hipStream_t stream) {
    const float* x     = (const float*)d_in[0];
    const float* mask  = (const float*)d_in[1];
    const float* msum  = (const float*)d_in[2];
    const float* msqrt = (const float*)d_in[3];
    const float* w1    = (const float*)d_in[4];
    const float* b1    = (const float*)d_in[5];
    const float* w2    = (const float*)d_in[6];
    const float* b2    = (const float*)d_in[7];
    float* out = (float*)d_out;

    k_se_fused<<<BB, 1024, 0, stream>>>(x, mask, msum, msqrt, w1, b1, w2, b2, out);
}